// Round 2
// baseline (974.214 us; speedup 1.0000x reference)
//
#include <hip/hip_runtime.h>
#include <hip/hip_bf16.h>

// Problem constants (ScaledDotProductAttention_33681133535371)
// query (32,16,512) f32 ; key (32,8192,512) f32 ; value (32,8192,512) f32 ;
// trust (32,1,8192) f32 ; out (32,1,512) f32
#define BATCH 32
#define QL    16
#define KL    8192
#define DIM   512
#define INV_SQRT_D 0.04419417382415922f  // 1/sqrt(512)

// ---------------------------------------------------------------------------
// Kernel 1: score[b][k] = (q0[b] . key[b][k]) / sqrt(D)
// grid (128, 32), block 256 (4 waves). Each wave: 16 consecutive keys.
// Lane owns dims lane*8..+7 (two float4 loads = 32B/lane, full 2KB row/wave).
// ---------------------------------------------------------------------------
__global__ __launch_bounds__(256) void k_scores(
    const float* __restrict__ query,
    const float* __restrict__ key,
    float* __restrict__ score)
{
    const int chunk = blockIdx.x;        // 64 keys per block
    const int b     = blockIdx.y;
    const int wv    = threadIdx.x >> 6;
    const int lane  = threadIdx.x & 63;

    const float* qp = query + (size_t)b * (QL * DIM) + lane * 8;
    const float4 qa = *(const float4*)qp;
    const float4 qb = *(const float4*)(qp + 4);

    const int kbase = chunk * 64 + wv * 16;
    const float* kp = key + ((size_t)b * KL + kbase) * DIM + lane * 8;
    float* sp = score + b * KL + kbase;

    #pragma unroll 4
    for (int i = 0; i < 16; ++i) {
        const float4 ka = *(const float4*)kp;
        const float4 kb = *(const float4*)(kp + 4);
        kp += DIM;
        float s;
        s = qa.x * ka.x;
        s = fmaf(qa.y, ka.y, s);
        s = fmaf(qa.z, ka.z, s);
        s = fmaf(qa.w, ka.w, s);
        s = fmaf(qb.x, kb.x, s);
        s = fmaf(qb.y, kb.y, s);
        s = fmaf(qb.z, kb.z, s);
        s = fmaf(qb.w, kb.w, s);
        #pragma unroll
        for (int off = 32; off > 0; off >>= 1) s += __shfl_xor(s, off, 64);
        if (lane == 0) sp[i] = s * INV_SQRT_D;
    }
}

// ---------------------------------------------------------------------------
// Kernel 2: per batch b: s_k = score_k * t_k ; m = max_k s_k ;
//           w_k = exp(s_k - m) * t_k / sum_j exp(s_j - m) * t_j
// (softmax denominator cancels against the post-multiply renormalization)
// grid (32), block 1024, 8 elements per thread.
// ---------------------------------------------------------------------------
__global__ __launch_bounds__(1024) void k_softmax(
    const float* __restrict__ score,
    const float* __restrict__ trust,
    float* __restrict__ w)
{
    const int b    = blockIdx.x;
    const int t    = threadIdx.x;        // 0..1023
    const int wv   = t >> 6;
    const int lane = t & 63;
    __shared__ float red[16];

    const float* sp = score + b * KL + t * 8;
    const float* tp = trust + b * KL + t * 8;
    const float4 sa = *(const float4*)sp;
    const float4 sb = *(const float4*)(sp + 4);
    const float4 ta = *(const float4*)tp;
    const float4 tb = *(const float4*)(tp + 4);
    float tv[8] = { ta.x, ta.y, ta.z, ta.w, tb.x, tb.y, tb.z, tb.w };
    float s[8]  = { sa.x * ta.x, sa.y * ta.y, sa.z * ta.z, sa.w * ta.w,
                    sb.x * tb.x, sb.y * tb.y, sb.z * tb.z, sb.w * tb.w };

    float m = s[0];
    #pragma unroll
    for (int j = 1; j < 8; ++j) m = fmaxf(m, s[j]);
    #pragma unroll
    for (int off = 32; off > 0; off >>= 1) m = fmaxf(m, __shfl_xor(m, off, 64));
    if (lane == 0) red[wv] = m;
    __syncthreads();
    m = red[0];
    #pragma unroll
    for (int i = 1; i < 16; ++i) m = fmaxf(m, red[i]);
    __syncthreads();   // red reused below

    float e[8];
    float loc = 0.f;
    #pragma unroll
    for (int j = 0; j < 8; ++j) { e[j] = __expf(s[j] - m) * tv[j]; loc += e[j]; }
    #pragma unroll
    for (int off = 32; off > 0; off >>= 1) loc += __shfl_xor(loc, off, 64);
    if (lane == 0) red[wv] = loc;
    __syncthreads();
    float S = 0.f;
    #pragma unroll
    for (int i = 0; i < 16; ++i) S += red[i];
    const float inv = 1.0f / S;

    float* wp = w + b * KL + t * 8;
    *(float4*)wp       = make_float4(e[0] * inv, e[1] * inv, e[2] * inv, e[3] * inv);
    *(float4*)(wp + 4) = make_float4(e[4] * inv, e[5] * inv, e[6] * inv, e[7] * inv);
}

// ---------------------------------------------------------------------------
// Kernel 3: partial context. grid (32 chunks, 32 batches), block 256 (4 waves).
// Block (c,b) covers keys c*256..c*256+255. Waves 0-1 take even key of each
// pair, waves 2-3 odd; thread owns 4 dims (float4 = 16B/lane loads).
// Each (block, half) writes its own partial slab — no atomics, deterministic.
// ---------------------------------------------------------------------------
__global__ __launch_bounds__(256) void k_pv(
    const float* __restrict__ value,
    const float* __restrict__ w,
    float* __restrict__ part)
{
    const int c    = blockIdx.x;          // key chunk
    const int b    = blockIdx.y;
    const int t    = threadIdx.x;         // 0..255
    const int half = t >> 7;              // 0 or 1 (wave-uniform)
    const int d4   = (t & 127) * 4;       // dim offset

    const float* vp = value + ((size_t)b * KL + c * 256 + half) * DIM + d4;
    const float* wp = w + b * KL + c * 256 + half;   // wave-uniform -> s_load
    float4 acc = make_float4(0.f, 0.f, 0.f, 0.f);
    #pragma unroll 8
    for (int i = 0; i < 128; ++i) {
        const float4 v = *(const float4*)vp;
        vp += 2 * DIM;
        const float wi = wp[i * 2];
        acc.x = fmaf(wi, v.x, acc.x);
        acc.y = fmaf(wi, v.y, acc.y);
        acc.z = fmaf(wi, v.z, acc.z);
        acc.w = fmaf(wi, v.w, acc.w);
    }
    float* pp = part + ((size_t)((b * 32 + c) * 2 + half)) * DIM + d4;
    *(float4*)pp = acc;
}

// ---------------------------------------------------------------------------
// Kernel 4: reduce 64 partial slabs per (b,d), write fp32. 16384 threads.
// ---------------------------------------------------------------------------
__global__ __launch_bounds__(256) void k_out(
    const float* __restrict__ part,
    float* __restrict__ out)
{
    const int idx = blockIdx.x * 256 + threadIdx.x;  // 0..16383
    const int b = idx >> 9;
    const int d = idx & 511;
    const float* pp = part + ((size_t)b * 64) * DIM + d;
    float s = 0.f;
    #pragma unroll
    for (int j = 0; j < 64; ++j) s += pp[j * DIM];
    out[idx] = s;
}

extern "C" void kernel_launch(void* const* d_in, const int* in_sizes, int n_in,
                              void* d_out, int out_size, void* d_ws, size_t ws_size,
                              hipStream_t stream) {
    const float* query = (const float*)d_in[0]; // (32,16,512) f32
    const float* key   = (const float*)d_in[1]; // (32,8192,512) f32
    const float* value = (const float*)d_in[2]; // (32,8192,512) f32
    const float* trust = (const float*)d_in[3]; // (32,1,8192) f32

    float* ws    = (float*)d_ws;
    float* score = ws;                        // 32*8192 f32 = 1 MB
    float* w     = ws + BATCH * KL;           // 32*8192 f32 = 1 MB
    float* part  = ws + 2 * BATCH * KL;       // 32*64*512 f32 = 4 MB

    k_scores<<<dim3(KL / 64, BATCH), 256, 0, stream>>>(query, key, score);
    k_softmax<<<dim3(BATCH), 1024, 0, stream>>>(score, trust, w);
    k_pv<<<dim3(32, BATCH), 256, 0, stream>>>(value, w, part);
    k_out<<<dim3(64), 256, 0, stream>>>(part, (float*)d_out);
}